// Round 8
// baseline (479.665 us; speedup 1.0000x reference)
//
#include <hip/hip_runtime.h>
#include <hip/hip_bf16.h>

typedef unsigned short u16;
typedef __attribute__((ext_vector_type(8))) short s16x8;   // 8 bf16 MFMA A/B frag
typedef __attribute__((ext_vector_type(4))) float f32x4;   // MFMA C/D frag

#define NN 20000
#define HH 64
#define EMBD 300
#define EE 160000
#define BB 4096
#define NODES 40000
#define SLST2 1280000  // NODES*32 (u16 units): one 32-feat slice region

// f32 param block offsets (floats) in workspace (after 16-float header)
#define OFF_PROJB 0
#define OFF_MSGB  64
#define OFF_BIH   192
#define OFF_BHH   576
#define OFF_CW1T  960
#define OFF_CB1   3008
#define OFF_CW2   3024
#define OFF_CB2   3040
#define PARAM_SZ  3072

// bf16 frag-swizzled weight blocks (u16 units). Each "frag" = 512 u16 = one
// 16(row)x32(k) B-tile stored so lane L reads its 8 elements at frag*512+L*8.
#define PB_WIH   0        // 2 l x 24 frags (jt 0..11, kt 0..1)
#define PB_WHH   24576
#define PB_WMT   49152    // 2 l x 8 frags (jt 0..3, kt 0..1)
#define PB_PROJT 57344    // 40 frags (frag = jt*10+kt, jt 0..3, kt 0..9)
#define PB_SZ    77824

// gstep LDS weight offsets (u16)
#define WIH_S 0
#define WHH_S 12288
#define WMT_S 24576

// projm LDS A-tile row stride (u16): 344 -> 172 dwords, <=2-way bank alias (free)
#define APAD 344

__device__ __forceinline__ float b2f(u16 u) {
    union { unsigned int i; float f; } v; v.i = ((unsigned int)u) << 16; return v.f;
}
__device__ __forceinline__ u16 f2b(float f) {
    union { float f; unsigned int u; } v; v.f = f;
    unsigned int u = v.u;
    return (u16)((u + 0x7FFFu + ((u >> 16) & 1u)) >> 16);   // RNE
}
__device__ __forceinline__ float ldf(const void* p, long long i, int isbf) {
    return isbf ? b2f(((const u16*)p)[i]) : ((const float*)p)[i];
}
__device__ __forceinline__ u16 ldb(const void* p, long long i, int isbf) {
    return isbf ? ((const u16*)p)[i] : f2b(((const float*)p)[i]);
}
__device__ __forceinline__ void stf(void* p, long long i, int isbf, float v) {
    if (isbf) ((u16*)p)[i] = f2b(v);
    else      ((float*)p)[i] = v;
}

// ---------------- dtype sniffer ----------------
__global__ void sniff_kernel(const u16* probe, int* flag)
{
    if (threadIdx.x == 0 && blockIdx.x == 0) {
        int good = 0;
        for (int i = 0; i < 128; i += 2) {
            unsigned int e = (probe[i] >> 7) & 0xFF;
            if (e >= 105 && e <= 127) good++;
        }
        *flag = (good >= 48) ? 1 : 0;
    }
}

// ---------------- param convert + frag swizzle (+ ioff zeroing) --------------
__global__ __launch_bounds__(256) void conv_kernel(
    const void* projW, const void* projb, const void* msgW, const void* msgb,
    const void* wih, const void* whh, const void* bih, const void* bhh,
    const void* cw1, const void* cb1, const void* cw2, const void* cb2,
    float* P, u16* PB, int* ioff, const int* flag)
{
    int isbf = *flag;
    int i = blockIdx.x * 256 + threadIdx.x;
    if (i < 2 * (NN + 1)) ioff[i] = 0;          // replaces hipMemsetAsync
    if (i < 64)    P[OFF_PROJB + i] = ldf(projb, i, isbf);
    if (i < 128)   P[OFF_MSGB + i]  = ldf(msgb, i, isbf);
    if (i < 384)   { P[OFF_BIH + i] = ldf(bih, i, isbf); P[OFF_BHH + i] = ldf(bhh, i, isbf); }
    if (i < 2048)  { int t = i >> 7, k = i & 127; P[OFF_CW1T + i] = ldf(cw1, (long long)k * 16 + t, isbf); }
    if (i < 16)    { P[OFF_CB1 + i] = ldf(cb1, i, isbf); P[OFF_CW2 + i] = ldf(cw2, i, isbf); }
    if (i == 0)    P[OFF_CB2] = ldf(cb2, 0, isbf);

    if (i < 24576) {   // Wih/Whh swizzle: per-l 24 frags
        int l = i / 12288, r = i - l * 12288;
        int frag = r >> 9, rr = r & 511, lane = rr >> 3, e = rr & 7;
        int jt = frag >> 1, kt = frag & 1;
        int srow = jt * 16 + (lane & 15);
        int sk = kt * 32 + ((lane >> 4) << 3) + e;
        long long si = (long long)l * 12288 + srow * 64 + sk;
        PB[PB_WIH + i] = ldb(wih, si, isbf);
        PB[PB_WHH + i] = ldb(whh, si, isbf);
    }
    if (i < 8192) {    // msgW^T swizzle
        int l = i >> 12, r = i & 4095;
        int frag = r >> 9, rr = r & 511, lane = rr >> 3, e = rr & 7;
        int jt = frag >> 1, kt = frag & 1;
        int srow = jt * 16 + (lane & 15);
        int sk = kt * 32 + ((lane >> 4) << 3) + e;
        PB[PB_WMT + i] = ldb(msgW, (long long)l * 4096 + sk * 64 + srow, isbf);
    }
    if (i < 20480) {   // projW^T swizzle, k zero-padded >=300
        int frag = i >> 9, rr = i & 511, lane = rr >> 3, e = rr & 7;
        int jt = frag / 10, kt = frag - jt * 10;
        int srow = jt * 16 + (lane & 15);
        int sk = kt * 32 + ((lane >> 4) << 3) + e;
        PB[PB_PROJT + i] = (sk < 300) ? ldb(projW, (long long)sk * 64 + srow, isbf) : (u16)0;
    }
}

// ---------------- CSR build ----------------
__global__ __launch_bounds__(256) void hist_kernel(const int* __restrict__ adj0,
                                                   const int* __restrict__ adj1, int* off)
{
    int e = blockIdx.x * 256 + threadIdx.x;
    if (e >= 2 * EE) return;
    int b = e / EE, le = e - b * EE;
    const int* adj = b ? adj1 : adj0;
    int tgt = adj[2 * le + 1];
    atomicAdd(&off[b * (NN + 1) + tgt + 1], 1);
}

__global__ __launch_bounds__(1024) void scan_kernel(int* off, int* cursor)
{
    int b = blockIdx.x;
    int* o = off + (size_t)b * (NN + 1);
    int* cur = cursor + (size_t)b * NN;
    __shared__ int wsum[16];
    __shared__ int wscan[16];
    int tid = threadIdx.x, wv = tid >> 6, lane = tid & 63;
    int base = 0;
    for (int start = 0; start < NN; start += 1024) {
        int i = start + tid;
        int v = (i < NN) ? o[i + 1] : 0;
        int orig = v;
        #pragma unroll
        for (int d = 1; d < 64; d <<= 1) {
            int t = __shfl_up(v, d);
            if (lane >= d) v += t;
        }
        if (lane == 63) wsum[wv] = v;
        __syncthreads();
        if (tid < 16) {
            int w = wsum[tid];
            #pragma unroll
            for (int d = 1; d < 16; d <<= 1) {
                int t = __shfl_up(w, d, 16);
                if (tid >= d) w += t;
            }
            wscan[tid] = w;
        }
        __syncthreads();
        int woff = (wv == 0) ? 0 : wscan[wv - 1];
        int excl = base + woff + v - orig;
        if (i < NN) { o[i] = excl; cur[i] = excl; }
        base += wscan[15];
    }
    if (tid == 0) o[NN] = base;
}

__global__ __launch_bounds__(256) void scatter_kernel(const int* __restrict__ adj0,
                                                      const int* __restrict__ adj1,
                                                      int* cursor, int* esrc)
{
    int e = blockIdx.x * 256 + threadIdx.x;
    if (e >= 2 * EE) return;
    int b = e / EE, le = e - b * EE;
    const int* adj = b ? adj1 : adj0;
    int src = adj[2 * le + 0];
    int tgt = adj[2 * le + 1];
    int pos = atomicAdd(&cursor[b * NN + tgt], 1);
    esrc[(size_t)b * EE + pos] = src;
}

// ---------------- embedding gather + projection (MFMA), 2x32-sliced output ---
__global__ __launch_bounds__(256) void projm_kernel(const void* emb,
                                                    const int* __restrict__ i0,
                                                    const int* __restrict__ i1,
                                                    const float* __restrict__ P,
                                                    const u16* __restrict__ PB,
                                                    u16* __restrict__ h, const int* flag)
{
    __shared__ u16 sA[64 * APAD];
    int isbf = *flag;
    int tid = threadIdx.x;
    int node0 = blockIdx.x * 64;

    // stage 64 embedding rows, 4 threads per row (wave w stages+reads rows 16w..16w+15)
    {
        int r = tid >> 2, sub = tid & 3;
        int n = node0 + r;
        int b = n >= NN;
        int ln = n - b * NN;
        int idx = b ? i1[ln] : i0[ln];
        if (isbf) {
            const ushort4* src = (const ushort4*)((const u16*)emb + (size_t)idx * EMBD);
            ushort4* dst = (ushort4*)(sA + r * APAD);
            for (int c = sub; c < 75; c += 4) dst[c] = src[c];
            if (sub == 0) {
                ushort4 z = {0, 0, 0, 0};
                for (int c = 75; c < 80; ++c) dst[c] = z;
            }
        } else {
            const float* src = (const float*)emb + (size_t)idx * EMBD;
            for (int k = sub; k < 300; k += 4) sA[r * APAD + k] = f2b(src[k]);
            if (sub == 0) for (int k = 300; k < 320; ++k) sA[r * APAD + k] = 0;
        }
    }

    int wv = tid >> 6, lane = tid & 63, quad = lane >> 4, cn = lane & 15;
    int m0 = wv * 16;
    f32x4 acc[4];
    #pragma unroll
    for (int j = 0; j < 4; ++j) {
        float bb = P[OFF_PROJB + j * 16 + cn];
        acc[j] = {bb, bb, bb, bb};
    }
    #pragma unroll
    for (int kt = 0; kt < 10; ++kt) {
        s16x8 a = *(const s16x8*)&sA[(m0 + cn) * APAD + kt * 32 + quad * 8];
        #pragma unroll
        for (int j = 0; j < 4; ++j) {
            s16x8 bfr = *(const s16x8*)&PB[PB_PROJT + (j * 10 + kt) * 512 + lane * 8];
            acc[j] = __builtin_amdgcn_mfma_f32_16x16x32_bf16(a, bfr, acc[j], 0, 0, 0);
        }
    }
    #pragma unroll
    for (int j = 0; j < 4; ++j)
        #pragma unroll
        for (int r = 0; r < 4; ++r)
            h[(size_t)(j >> 1) * SLST2 + (size_t)(node0 + m0 + quad * 4 + r) * 32
              + (j & 1) * 16 + cn] = f2b(acc[j][r]);
}

// ---------------- neighbor gather-sum, 2x32 XCD-sliced ------------------------
// grid = 2 slices x 5000 node-tiles; slice = blockIdx&1 -> even/odd XCDs under
// round-robin dispatch; per-XCD working set = 2.5 MB slice region (L2-resident).
// Block = 8 nodes x 32 feats: 64-B granules, half the requests of 16-feat slices.
__global__ __launch_bounds__(256) void gatherS_kernel(const u16* __restrict__ h_old,
                                                      u16* __restrict__ Sbuf,
                                                      const int* __restrict__ ioff,
                                                      const int* __restrict__ esrc)
{
    int b = blockIdx.x;
    int slice = b & 1;
    int tile = b >> 1;                 // 0..4999
    int tid = threadIdx.x;
    int i = tid >> 5, feat = tid & 31;
    int node = tile * 8 + i;           // 0..39999 exact
    int br = node >= NN;
    int ln = node - br * NN;
    const int* o = ioff + (size_t)br * (NN + 1);
    int s0 = o[ln], s1 = o[ln + 1];
    const int* es = esrc + (size_t)br * EE;
    const u16* hb = h_old + (size_t)slice * SLST2 + (size_t)br * NN * 32;
    float a0 = 0.f, a1 = 0.f, a2 = 0.f, a3 = 0.f;
    int e = s0;
    for (; e + 4 <= s1; e += 4) {
        int e0 = es[e], e1 = es[e + 1], e2 = es[e + 2], e3 = es[e + 3];
        a0 += b2f(hb[(size_t)e0 * 32 + feat]);
        a1 += b2f(hb[(size_t)e1 * 32 + feat]);
        a2 += b2f(hb[(size_t)e2 * 32 + feat]);
        a3 += b2f(hb[(size_t)e3 * 32 + feat]);
    }
    for (; e < s1; ++e) a0 += b2f(hb[(size_t)es[e] * 32 + feat]);
    Sbuf[(size_t)slice * SLST2 + (size_t)node * 32 + feat] = f2b(a0 + a1 + a2 + a3);
}

// ---------------- GRU step (MFMA; LDS-staged weights; sliced S/h I/O) --------
__global__ __launch_bounds__(256) void gstep_kernel(const u16* __restrict__ Sbuf,
                                                    const u16* __restrict__ h_old,
                                                    u16* __restrict__ h_new,
                                                    const int* __restrict__ ioff,
                                                    const float* __restrict__ P,
                                                    const u16* __restrict__ PB, int l)
{
    __shared__ u16 s_W[28672];     // Wih 12288 | Whh 12288 | msgWT 4096 (56 KB)
    __shared__ u16 s_S[4096];
    __shared__ u16 s_h[4096];
    __shared__ float s_deg[64];

    int tid = threadIdx.x;
    int wv = tid >> 6, lane = tid & 63;
    int node0 = blockIdx.x * 64;
    int m0 = wv * 16;

    // co-stage layer weights once per block (block-invariant, shared by waves)
    {
        const uint4* a = (const uint4*)(PB + PB_WIH + (size_t)l * 12288);
        const uint4* bq = (const uint4*)(PB + PB_WHH + (size_t)l * 12288);
        uint4* da = (uint4*)(s_W + WIH_S);
        uint4* db = (uint4*)(s_W + WHH_S);
        for (int i = tid; i < 1536; i += 256) { da[i] = a[i]; db[i] = bq[i]; }
        const uint4* cq = (const uint4*)(PB + PB_WMT + (size_t)l * 4096);
        uint4* dc = (uint4*)(s_W + WMT_S);
        for (int i = tid; i < 512; i += 256) dc[i] = cq[i];
    }

    // stage own rows (wave-private) from 2x32-sliced layout into node-major LDS
    #pragma unroll
    for (int it = 0; it < 2; ++it) {
        int c = it * 64 + lane;        // 0..127 = row(16) x slice(2) x part(4)
        int row = c >> 3, q = c & 7;
        int slice = q >> 2, part = q & 3;
        size_t goff = (size_t)slice * SLST2 + (size_t)(node0 + m0 + row) * 32 + part * 8;
        *(uint4*)(s_h + (m0 + row) * 64 + slice * 32 + part * 8) = *(const uint4*)(h_old + goff);
        *(uint4*)(s_S + (m0 + row) * 64 + slice * 32 + part * 8) = *(const uint4*)(Sbuf + goff);
    }
    if (lane < 16) {
        int row = m0 + lane;
        int n = node0 + row;
        int br = n >= NN;
        int ln = n - br * NN;
        const int* o = ioff + (size_t)br * (NN + 1);
        s_deg[row] = (float)(o[ln + 1] - o[ln]);
    }
    __syncthreads();   // weights visible to all waves (tiles are wave-private anyway)

    int quad = lane >> 4, cn = lane & 15;
    int arow = (m0 + cn) * 64 + quad * 8;
    int fl = lane * 8;

    // phase 1: inc = S @ msgW + deg*msgb (wave-private rows, alias-safe)
    s16x8 aS0 = *(const s16x8*)&s_S[arow];
    s16x8 aS1 = *(const s16x8*)&s_S[arow + 32];
    #pragma unroll
    for (int jt = 0; jt < 4; ++jt) {
        float mb = P[OFF_MSGB + l * 64 + jt * 16 + cn];
        f32x4 acc;
        acc[0] = s_deg[m0 + quad * 4 + 0] * mb;
        acc[1] = s_deg[m0 + quad * 4 + 1] * mb;
        acc[2] = s_deg[m0 + quad * 4 + 2] * mb;
        acc[3] = s_deg[m0 + quad * 4 + 3] * mb;
        acc = __builtin_amdgcn_mfma_f32_16x16x32_bf16(aS0, *(const s16x8*)&s_W[WMT_S + (jt * 2 + 0) * 512 + fl], acc, 0, 0, 0);
        acc = __builtin_amdgcn_mfma_f32_16x16x32_bf16(aS1, *(const s16x8*)&s_W[WMT_S + (jt * 2 + 1) * 512 + fl], acc, 0, 0, 0);
        #pragma unroll
        for (int r = 0; r < 4; ++r)
            s_S[(m0 + quad * 4 + r) * 64 + jt * 16 + cn] = f2b(acc[r]);
    }

    // phase 2+3: gi/gh GEMMs (B-frags from LDS) + fused GRU
    s16x8 aI0 = *(const s16x8*)&s_S[arow];
    s16x8 aI1 = *(const s16x8*)&s_S[arow + 32];
    s16x8 aH0 = *(const s16x8*)&s_h[arow];
    s16x8 aH1 = *(const s16x8*)&s_h[arow + 32];
    const float* bi = P + OFF_BIH + l * 192;
    const float* bh = P + OFF_BHH + l * 192;

    #pragma unroll
    for (int c = 0; c < 4; ++c) {
        int j0 = c * 16;
        float vr = bi[j0 + cn], vz = bi[64 + j0 + cn], vn = bi[128 + j0 + cn];
        float wr = bh[j0 + cn], wz = bh[64 + j0 + cn], wn = bh[128 + j0 + cn];
        f32x4 gr = {vr, vr, vr, vr}, gz = {vz, vz, vz, vz}, gn = {vn, vn, vn, vn};
        f32x4 hr = {wr, wr, wr, wr}, hz = {wz, wz, wz, wz}, hn = {wn, wn, wn, wn};
        int fr  = WIH_S + (c * 2) * 512 + fl;
        int frz = WIH_S + ((4 + c) * 2) * 512 + fl;
        int frn = WIH_S + ((8 + c) * 2) * 512 + fl;
        int hrr = WHH_S + (c * 2) * 512 + fl;
        int hrz = WHH_S + ((4 + c) * 2) * 512 + fl;
        int hrn = WHH_S + ((8 + c) * 2) * 512 + fl;
        gr = __builtin_amdgcn_mfma_f32_16x16x32_bf16(aI0, *(const s16x8*)&s_W[fr], gr, 0, 0, 0);
        gr = __builtin_amdgcn_mfma_f32_16x16x32_bf16(aI1, *(const s16x8*)&s_W[fr + 512], gr, 0, 0, 0);
        gz = __builtin_amdgcn_mfma_f32_16x16x32_bf16(aI0, *(const s16x8*)&s_W[frz], gz, 0, 0, 0);
        gz = __builtin_amdgcn_mfma_f32_16x16x32_bf16(aI1, *(const s16x8*)&s_W[frz + 512], gz, 0, 0, 0);
        gn = __builtin_amdgcn_mfma_f32_16x16x32_bf16(aI0, *(const s16x8*)&s_W[frn], gn, 0, 0, 0);
        gn = __builtin_amdgcn_mfma_f32_16x16x32_bf16(aI1, *(const s16x8*)&s_W[frn + 512], gn, 0, 0, 0);
        hr = __builtin_amdgcn_mfma_f32_16x16x32_bf16(aH0, *(const s16x8*)&s_W[hrr], hr, 0, 0, 0);
        hr = __builtin_amdgcn_mfma_f32_16x16x32_bf16(aH1, *(const s16x8*)&s_W[hrr + 512], hr, 0, 0, 0);
        hz = __builtin_amdgcn_mfma_f32_16x16x32_bf16(aH0, *(const s16x8*)&s_W[hrz], hz, 0, 0, 0);
        hz = __builtin_amdgcn_mfma_f32_16x16x32_bf16(aH1, *(const s16x8*)&s_W[hrz + 512], hz, 0, 0, 0);
        hn = __builtin_amdgcn_mfma_f32_16x16x32_bf16(aH0, *(const s16x8*)&s_W[hrn], hn, 0, 0, 0);
        hn = __builtin_amdgcn_mfma_f32_16x16x32_bf16(aH1, *(const s16x8*)&s_W[hrn + 512], hn, 0, 0, 0);
        #pragma unroll
        for (int r = 0; r < 4; ++r) {
            int row = m0 + quad * 4 + r;
            float rr = 1.f / (1.f + __expf(-(gr[r] + hr[r])));
            float zz = 1.f / (1.f + __expf(-(gz[r] + hz[r])));
            float xx = gn[r] + rr * hn[r];
            float tv = __expf(-2.f * fabsf(xx));
            float nn = __builtin_copysignf((1.f - tv) / (1.f + tv), xx);
            float ho = b2f(s_h[row * 64 + j0 + cn]);
            h_new[(size_t)(c >> 1) * SLST2 + (size_t)(node0 + row) * 32 + (c & 1) * 16 + cn]
                = f2b((1.f - zz) * nn + zz * ho);
        }
    }
}

// ---------------- classifier: wave-per-sample (2x32-sliced h reads) -----------
__global__ __launch_bounds__(256) void cls_kernel(const u16* __restrict__ h,
                                                  const int* __restrict__ p0,
                                                  const int* __restrict__ p1,
                                                  const int* __restrict__ labels,
                                                  const float* __restrict__ P,
                                                  void* out, float* partial, const int* flag)
{
    int isbf = *flag;
    int wv = threadIdx.x >> 6, lane = threadIdx.x & 63;
    int s = blockIdx.x * 4 + wv;               // 1024 blocks x 4 waves = 4096
    int n0 = p0[s], n1 = p1[s];
    size_t sl = (size_t)(lane >> 5) * SLST2;
    int off = lane & 31;
    float f0 = b2f(h[sl + (size_t)n0 * 32 + off]);
    float f1 = b2f(h[sl + (size_t)(NN + n1) * 32 + off]);
    float z = P[OFF_CB2];
    #pragma unroll
    for (int t = 0; t < 16; ++t) {
        float part = f0 * P[OFF_CW1T + t * 128 + lane] + f1 * P[OFF_CW1T + t * 128 + 64 + lane];
        #pragma unroll
        for (int o2 = 32; o2; o2 >>= 1) part += __shfl_xor(part, o2);
        z += fmaxf(part + P[OFF_CB1 + t], 0.f) * P[OFF_CW2 + t];
    }
    float p = 1.f / (1.f + expf(-z));
    float y = (float)labels[s];
    const float eps = 1e-7f;
    float pc  = fminf(fmaxf(p, eps), 1.f);
    float pc1 = fminf(fmaxf(1.f - p, eps), 1.f);
    float term = y * logf(pc) + (1.f - y) * logf(pc1);
    __shared__ float red[4];
    if (lane == 0) { stf(out, s, isbf, p); red[wv] = term; }
    __syncthreads();
    if (threadIdx.x == 0) partial[blockIdx.x] = red[0] + red[1] + red[2] + red[3];
}

__global__ __launch_bounds__(256) void loss_kernel(const float* __restrict__ partial,
                                                   void* out, const int* flag)
{
    __shared__ float red[256];
    int tid = threadIdx.x;
    float s = 0.f;
    for (int i = tid; i < 1024; i += 256) s += partial[i];
    red[tid] = s;
    __syncthreads();
    for (int d = 128; d > 0; d >>= 1) {
        if (tid < d) red[tid] += red[tid + d];
        __syncthreads();
    }
    if (tid == 0) stf(out, BB, *flag, -red[0] / (float)BB);
}

extern "C" void kernel_launch(void* const* d_in, const int* in_sizes, int n_in,
                              void* d_out, int out_size, void* d_ws, size_t ws_size,
                              hipStream_t stream)
{
    const int* adj0   = (const int*)d_in[2];
    const int* adj1   = (const int*)d_in[3];
    const int* prop0  = (const int*)d_in[4];
    const int* prop1  = (const int*)d_in[5];
    const int* labels = (const int*)d_in[6];

    int* flag = (int*)d_ws;
    float* P  = (float*)d_ws + 16;
    u16* PB   = (u16*)(P + PARAM_SZ);
    u16* h0   = PB + PB_SZ;                    // 2 slices x 40000 x 32 bf16
    u16* h1   = h0 + (size_t)2 * SLST2;
    u16* SB   = h1 + (size_t)2 * SLST2;
    float* partial = (float*)(SB + (size_t)2 * SLST2);
    int* ioff   = (int*)(partial + 1024);
    int* cursor = ioff + 2 * (NN + 1) + 62;
    int* esrc   = cursor + 2 * NN;

    sniff_kernel<<<1, 64, 0, stream>>>((const u16*)d_in[8], flag);
    conv_kernel<<<157, 256, 0, stream>>>(d_in[8], d_in[9], d_in[10], d_in[11], d_in[12], d_in[13],
                                         d_in[14], d_in[15], d_in[16], d_in[17], d_in[18], d_in[19],
                                         P, PB, ioff, flag);
    hist_kernel<<<(2 * EE) / 256, 256, 0, stream>>>(adj0, adj1, ioff);
    scan_kernel<<<2, 1024, 0, stream>>>(ioff, cursor);
    scatter_kernel<<<(2 * EE) / 256, 256, 0, stream>>>(adj0, adj1, cursor, esrc);
    projm_kernel<<<NODES / 64, 256, 0, stream>>>(d_in[7], (const int*)d_in[0],
                                                 (const int*)d_in[1], P, PB, h0, flag);

    u16* hcur = h0;
    u16* hnext = h1;
    for (int l = 0; l < 2; ++l) {
        for (int t = 0; t < 3; ++t) {
            gatherS_kernel<<<2 * (NODES / 8), 256, 0, stream>>>(hcur, SB, ioff, esrc);
            gstep_kernel<<<NODES / 64, 256, 0, stream>>>(SB, hcur, hnext, ioff, P, PB, l);
            u16* tmp = hcur; hcur = hnext; hnext = tmp;
        }
    }
    // 6 steps -> final state back in h0 (== hcur)

    cls_kernel<<<BB / 4, 256, 0, stream>>>(hcur, prop0, prop1, labels, P, d_out, partial, flag);
    loss_kernel<<<1, 256, 0, stream>>>(partial, d_out, flag);
}